// Round 16
// baseline (1704.579 us; speedup 1.0000x reference)
//
#include <hip/hip_runtime.h>
#include <hip/hip_bf16.h>

// CTRNN: T=512, B=64, I=512, H=1024 — two dispatches.
//   1) xproj: round-8 version verbatim (grid (16,512), proven ~170us).
//   2) rnn_persist: round-8 protocol with PER-WAVE flags:
//      - epilogue remap: lane l -> brow=l>>2, c0=16w+4(l&3), so wave w fully owns
//        ring granules kc=8g+2w, 8g+2w+1 (16 rows x 8 shorts each).
//      - each wave: ring store -> own vmcnt(0) -> raise flags[bid*4+w] (BEFORE
//        barrier B) -> tail -> barrier B (Pr reuse guard).
//      - consumer wave w polls the 16 exact producer-wave flags:
//        lane l -> flags[(4*(4w+(l&3))+r)*4 + ((l>>2)&3)].
//      Same 2-deep ring + >=1-step overwrite slack as the proven block-flag chain.

typedef __attribute__((ext_vector_type(8))) short short8;
typedef __attribute__((ext_vector_type(4))) float f32x4;
typedef unsigned long long ull;

#define TT 512
#define BB 64
#define II 512
#define HH 1024

__device__ __forceinline__ short f2bf(float f) {
  unsigned u = __builtin_bit_cast(unsigned, f);
  u += 0x7fffu + ((u >> 16) & 1u);   // RNE
  return (short)(u >> 16);
}

// ---------------- xproj: grid (16 nblk, 512 mblk), 256 thr, block tile 64m x 64n
__global__ __launch_bounds__(256) void xproj_kernel(
    const float* __restrict__ x, const float* __restrict__ Win,
    const float* __restrict__ bin, const float* __restrict__ bhh,
    float* __restrict__ out) {
  __shared__ short Wl[64 * 256];
  const int tid = threadIdx.x;
  const int l = tid & 63, w = tid >> 6;
  const int lr = l & 15, lg = l >> 4;
  const int n0 = blockIdx.x * 64;
  const int m0 = blockIdx.y * 64;

  f32x4 acc[4];
  #pragma unroll
  for (int i = 0; i < 4; ++i) acc[i] = (f32x4){0.f, 0.f, 0.f, 0.f};

  const float* arow = x + (size_t)(m0 + w * 16 + lr) * II + lg * 8;

  for (int ks = 0; ks < II; ks += 256) {
    for (int i = tid; i < 4096; i += 256) {
      int e = i << 2;
      int r = e >> 8;
      int c = e & 255;
      float4 v = *(const float4*)(Win + (size_t)(n0 + r) * II + ks + c);
      int c8 = c >> 3;
      int dst = r * 256 + ((c8 ^ (r & 7)) << 3) + (c & 7);
      Wl[dst + 0] = f2bf(v.x); Wl[dst + 1] = f2bf(v.y);
      Wl[dst + 2] = f2bf(v.z); Wl[dst + 3] = f2bf(v.w);
    }
    __syncthreads();
    #pragma unroll
    for (int k0 = 0; k0 < 256; k0 += 32) {
      float4 a0 = *(const float4*)(arow + ks + k0);
      float4 a1 = *(const float4*)(arow + ks + k0 + 4);
      short8 af;
      af[0] = f2bf(a0.x); af[1] = f2bf(a0.y); af[2] = f2bf(a0.z); af[3] = f2bf(a0.w);
      af[4] = f2bf(a1.x); af[5] = f2bf(a1.y); af[6] = f2bf(a1.z); af[7] = f2bf(a1.w);
      int kc = (k0 >> 3) + lg;
      #pragma unroll
      for (int ns = 0; ns < 4; ++ns) {
        int r = ns * 16 + lr;
        short8 bf = *(const short8*)(&Wl[r * 256 + (((kc) ^ (r & 7)) << 3)]);
        acc[ns] = __builtin_amdgcn_mfma_f32_16x16x32_bf16(af, bf, acc[ns], 0, 0, 0);
      }
    }
    __syncthreads();
  }

  #pragma unroll
  for (int ns = 0; ns < 4; ++ns) {
    int n = n0 + ns * 16 + lr;
    float bias = bin[n] + bhh[n];
    #pragma unroll
    for (int j = 0; j < 4; ++j) {
      int m = m0 + w * 16 + lg * 4 + j;
      out[(size_t)m * HH + n] = acc[ns][j] + bias;
    }
  }
}

// ---------------- persistent recurrence, per-wave flags
// ring bf16 layout: granule (r*128 + kc)*16 + row16, 8 shorts each; kc = k/8.
__global__ __launch_bounds__(256) void rnn_persist(
    const float* __restrict__ h0, const float* __restrict__ Whh,
    float* __restrict__ out, short* __restrict__ ring0,
    short* __restrict__ ring1, int* __restrict__ flags) {
  __shared__ short Wl[64 * 1024];   // fragment (kc,n) at (kc*64+n)*8 shorts, 128 KB
  __shared__ float Pr[4 * 16 * 68]; // per-wave K-partials, stride 68 (anti-conflict)

  const int bid = blockIdx.x;
  const int r = bid & 3, g = bid >> 2;
  const int tid = threadIdx.x;
  const int l = tid & 63, w = tid >> 6;
  const int lr = l & 15, lg = l >> 4;

  // stage W_hh rows (output cols) [64g, 64g+64), K-major bf16 fragments
  const int n0 = g * 64;
  for (int j = 0; j < 32; ++j) {
    int c = j * 256 + tid;           // c = n*128 + kc
    int kc = c & 127, n = c >> 7;
    const float* src = Whh + (size_t)(n0 + n) * HH + kc * 8;
    float4 v0 = *(const float4*)src;
    float4 v1 = *(const float4*)(src + 4);
    short* d = Wl + (((size_t)kc * 64 + n) << 3);
    d[0] = f2bf(v0.x); d[1] = f2bf(v0.y); d[2] = f2bf(v0.z); d[3] = f2bf(v0.w);
    d[4] = f2bf(v1.x); d[5] = f2bf(v1.y); d[6] = f2bf(v1.z); d[7] = f2bf(v1.w);
  }

  // epilogue thread tile (wave-owns-granule remap):
  //   brow = l>>2 (0..15), c0 = 16w + 4(l&3)  ->  wave w owns kc_local 2w, 2w+1
  const int brow = l >> 2;
  const int c0 = 16 * w + 4 * (l & 3);
  const size_t oidx = (size_t)(16 * r + brow) * HH + n0 + c0;
  const size_t ringoff =
      (((size_t)(r * 128 + 8 * g + (c0 >> 3)) * 16 + brow) << 3) + (c0 & 7);

  // init ring0 from h0; carry own h in register
  f32x4 hpv;
  {
    float4 v = *(const float4*)(h0 + oidx);
    hpv[0] = v.x; hpv[1] = v.y; hpv[2] = v.z; hpv[3] = v.w;
    ull u = (ull)(unsigned short)f2bf(v.x)
          | ((ull)(unsigned short)f2bf(v.y) << 16)
          | ((ull)(unsigned short)f2bf(v.z) << 32)
          | ((ull)(unsigned short)f2bf(v.w) << 48);
    __hip_atomic_store((ull*)(ring0 + ringoff), u,
                       __ATOMIC_RELAXED, __HIP_MEMORY_SCOPE_AGENT);
  }
  // prefetch x_proj[0] (plain load)
  f32x4 xpv;
  {
    float4 v = *(const float4*)(out + oidx);
    xpv[0] = v.x; xpv[1] = v.y; xpv[2] = v.z; xpv[3] = v.w;
  }
  __syncthreads();  // drains vmcnt: init ring stores at coherence point
  if ((tid & 63) == 0)
    __hip_atomic_store(&flags[bid * 4 + w], 1,
                       __ATOMIC_RELAXED, __HIP_MEMORY_SCOPE_AGENT);

  // consumer wave w reads kc in [32w,32w+32) -> producer waves:
  //   block (r, 4w+(l&3)), wave (l>>2)&3
  const int fidx = (4 * (4 * w + (l & 3)) + r) * 4 + ((l >> 2) & 3);
  const short* bW = Wl + ((((size_t)(32 * w + lg)) * 64 + lr) << 3);
  const size_t abase = ((((size_t)(r * 128 + 32 * w + lg)) * 16 + lr) << 3);

  for (int t = 0; t < TT; ++t) {
    short* rc = (t & 1) ? ring1 : ring0;
    short* rn = (t & 1) ? ring0 : ring1;
    float* outt = out + (size_t)t * (BB * HH);

    // 1. wait for this wave's 16 producer WAVES to have published h_t
    {
      int target = t + 1;
      while (!__all(__hip_atomic_load(&flags[fidx], __ATOMIC_RELAXED,
                                      __HIP_MEMORY_SCOPE_AGENT) >= target))
        __builtin_amdgcn_s_sleep(1);
    }

    // 2. coherent A loads of this wave's K-slice (kc = 32w+lg+4i)
    const short* ar = rc + abase;
    const short* ar2 = ar + 2048;  // +4096 bytes
    int4 fa[8];
#define LDA(I, BASE, OFF) \
    asm volatile("global_load_dwordx4 %0, %1, off offset:%2 sc0 sc1" \
                 : "=v"(fa[I]) : "v"(BASE), "n"(OFF))
    LDA(0, ar, 0); LDA(1, ar, 1024); LDA(2, ar, 2048); LDA(3, ar, 3072);
    LDA(4, ar2, 0); LDA(5, ar2, 1024); LDA(6, ar2, 2048); LDA(7, ar2, 3072);
#undef LDA
    asm volatile("s_waitcnt vmcnt(0)" ::: "memory");
    __builtin_amdgcn_sched_barrier(0);

    // 3. MFMA over this wave's 32 kc slices
    f32x4 acc[4];
    acc[0] = acc[1] = acc[2] = acc[3] = (f32x4){0.f, 0.f, 0.f, 0.f};
    #pragma unroll
    for (int i = 0; i < 8; ++i) {
      short8 a = __builtin_bit_cast(short8, fa[i]);
      acc[0] = __builtin_amdgcn_mfma_f32_16x16x32_bf16(
          a, *(const short8*)(bW + i * 2048 + 0),   acc[0], 0, 0, 0);
      acc[1] = __builtin_amdgcn_mfma_f32_16x16x32_bf16(
          a, *(const short8*)(bW + i * 2048 + 128), acc[1], 0, 0, 0);
      acc[2] = __builtin_amdgcn_mfma_f32_16x16x32_bf16(
          a, *(const short8*)(bW + i * 2048 + 256), acc[2], 0, 0, 0);
      acc[3] = __builtin_amdgcn_mfma_f32_16x16x32_bf16(
          a, *(const short8*)(bW + i * 2048 + 384), acc[3], 0, 0, 0);
    }

    // 4. publish K-partials: D row = lg*4+jj (batch), col = nt*16+lr
    float* pw = Pr + w * 1088;
    #pragma unroll
    for (int nt = 0; nt < 4; ++nt) {
      #pragma unroll
      for (int jj = 0; jj < 4; ++jj)
        pw[(lg * 4 + jj) * 68 + nt * 16 + lr] = acc[nt][jj];
    }
    __syncthreads();   // barrier A: Pr writes -> reads

    // 5. reduce 4 K-partials + sigmoid update (xpv, hpv carried in regs)
    const float* pb = Pr + brow * 68 + c0;
    f32x4 s = *(const f32x4*)(pb)
            + *(const f32x4*)(pb + 1088)
            + *(const f32x4*)(pb + 2176)
            + *(const f32x4*)(pb + 3264);
    f32x4 hn;
    #pragma unroll
    for (int k = 0; k < 4; ++k) {
      float pre = s[k] + xpv[k];
      float sg = 1.f / (1.f + __expf(-pre));
      hn[k] = 0.8f * hpv[k] + 0.2f * sg;  // 1-ALPHA, ALPHA, GAIN=1
    }

    // 6. publish h_{t+1}: this wave's own granules only (one 8B store/thread)
    {
      ull u = (ull)(unsigned short)f2bf(hn[0])
            | ((ull)(unsigned short)f2bf(hn[1]) << 16)
            | ((ull)(unsigned short)f2bf(hn[2]) << 32)
            | ((ull)(unsigned short)f2bf(hn[3]) << 48);
      __hip_atomic_store((ull*)(rn + ringoff), u,
                         __ATOMIC_RELAXED, __HIP_MEMORY_SCOPE_AGENT);
    }
    // 7. per-wave: drain own ring stores, raise own wave-flag (no barrier wait)
    asm volatile("s_waitcnt vmcnt(0)" ::: "memory");
    if ((tid & 63) == 0)
      __hip_atomic_store(&flags[bid * 4 + w], t + 2,
                         __ATOMIC_RELAXED, __HIP_MEMORY_SCOPE_AGENT);

    // 8. non-critical tail: out store, h_last, next xp prefetch
    *(float4*)(outt + oidx) = *(float4*)&hn;
    if (t == TT - 1) {
      *(float4*)(out + (size_t)TT * BB * HH + oidx) = *(float4*)&hn;
    } else {
      float4 v = *(const float4*)(outt + BB * HH + oidx);
      xpv[0] = v.x; xpv[1] = v.y; xpv[2] = v.z; xpv[3] = v.w;
    }
    hpv = hn;

    __syncthreads();   // barrier B: Pr reuse guard for next iteration
  }
}

extern "C" void kernel_launch(void* const* d_in, const int* in_sizes, int n_in,
                              void* d_out, int out_size, void* d_ws, size_t ws_size,
                              hipStream_t stream) {
  const float* x   = (const float*)d_in[0];
  const float* h0  = (const float*)d_in[1];
  const float* Win = (const float*)d_in[2];
  const float* bin = (const float*)d_in[3];
  const float* Whh = (const float*)d_in[4];
  const float* bhh = (const float*)d_in[5];
  float* out = (float*)d_out;

  int* flags = (int*)d_ws;                        // 256 ints (per-wave), 1 KB
  short* ring0 = (short*)((char*)d_ws + 1024);    // 128 KB
  short* ring1 = ring0 + BB * HH;                 // 128 KB

  hipMemsetAsync(d_ws, 0, 1024, stream);
  xproj_kernel<<<dim3(16, 512), 256, 0, stream>>>(x, Win, bin, bhh, out);
  rnn_persist<<<dim3(64), 256, 0, stream>>>(h0, Whh, out, ring0, ring1, flags);
}